// Round 7
// baseline (110.843 us; speedup 1.0000x reference)
//
#include <hip/hip_runtime.h>

#define EPS 1e-7f
#define T_DIM 2048
#define TP1   2049
#define H_DIM 8
#define B_DIM 8

#define NFRAG 148          // fb_phys in [0,148): b0 = fbp*16 - 192 (first 12 entries zero pad)
#define NST   34           // 64-wide s-tiles per b (covers s in [0,2176), zero past 2048)
#define AREG  14336        // A region bytes per LDS buffer (14 x 1KB entries)
#define BUFSZ 47104        // A 14KB + B 4 x 8KB (2 b x 2 s-tiles)
#define RSTRIDE 66         // post-loop LDS reduction row stride

#define J1_BLOCKS 296      // 8*148*64/256 fragA entries
#define J2_BLOCKS 272      // 8 b * 34 st transpose tiles
#define J3_BLOCKS 4098     // head-H rows: 8*2049/4
#define MM_BLOCKS 544      // 17 t0-levels * 4 b-groups * 8 heads

typedef short v8s __attribute__((ext_vector_type(8)));
typedef float v4f __attribute__((ext_vector_type(4)));

static __device__ __forceinline__ unsigned short f2bf(float f) {
  union { float f; unsigned u; } v; v.f = f;
  unsigned r = v.u + 0x7fffu + ((v.u >> 16) & 1u);  // RTNE
  return (unsigned short)(r >> 16);
}

static __device__ __forceinline__ void load_lds16(const void* g, void* l) {
  __builtin_amdgcn_global_load_lds(
      (const __attribute__((address_space(1))) unsigned int*)g,
      (__attribute__((address_space(3))) unsigned int*)l, 16, 0, 0);
}

// prep: [J1] MFMA A-fragment table, [J2] x -> bf16 transpose into swizzled 8KB
// chunks xT[b][st][dd][slot^(dd&7)][8], [J3] head-H l2norm output.
__global__ __launch_bounds__(256) void prep(const float* __restrict__ x,
                                            const float* __restrict__ W,
                                            unsigned short* __restrict__ fragA,
                                            unsigned short* __restrict__ xT,
                                            float* __restrict__ out) {
  __shared__ float tile[64][65];
  int bid = blockIdx.x;
  if (bid < J1_BLOCKS) {
    // fragA[((h*NFRAG+fbp)*64+lane)*8]: A[m=lm][k=8q+j] = k_h[b0+lm-8q-j], b0=fbp*16-192
    int tid = bid * 256 + threadIdx.x;
    int blk = tid >> 6, lane = tid & 63;
    int h = blk / NFRAG, fbp = blk - h * NFRAG;
    int b0 = fbp * 16 - 192;
    int lm = lane & 15, quad = lane >> 4;
    v8s frag;
    #pragma unroll
    for (int j = 0; j < 8; ++j) {
      int d = b0 + lm - 8 * quad - j;
      float v = 0.0f;
      if (d >= 0 && d < T_DIM) v = __expf(W[d * H_DIM + h]);
      else if (d == T_DIM) v = 1.0f;
      frag[j] = (short)f2bf(v);
    }
    *(v8s*)(fragA + (size_t)tid * 8) = frag;
    return;
  }
  bid -= J1_BLOCKS;
  if (bid < J2_BLOCKS) {
    int b = bid / NST, st = bid - b * NST;
    int s0 = st * 64;
    int tid = threadIdx.x;
    int c = tid & 63, r4 = tid >> 6;
    #pragma unroll
    for (int i = 0; i < 16; ++i) {
      int sl = r4 * 16 + i;
      int s = s0 + sl;
      tile[sl][c] = (s < T_DIM) ? x[((size_t)b * T_DIM + s) * 64 + c] : 0.0f;
    }
    __syncthreads();
    // chunk byte layout: dd*128 + p*16 + j*2 holds s_local = (p^(dd&7))*8 + j
    int dd = tid >> 2, pb = (tid & 3) * 2;
    unsigned short* dst = xT + ((size_t)(b * NST + st) << 12) + dd * 64;
    #pragma unroll
    for (int e = 0; e < 2; ++e) {
      int p = pb + e;
      int sb = ((p ^ (dd & 7)) << 3);
      v8s o;
      #pragma unroll
      for (int j = 0; j < 8; ++j) o[j] = (short)f2bf(tile[sb + j][dd]);
      *(v8s*)(dst + p * 8) = o;
    }
    return;
  }
  bid -= J2_BLOCKS;
  {  // head H: single l2norm of xp
    int row = bid * 4 + (threadIdx.x >> 6);
    if (row >= B_DIM * TP1) return;
    int b = row / TP1, t = row - b * TP1;
    int dd = threadIdx.x & 63;
    float v = (t < T_DIM) ? x[((size_t)b * T_DIM + t) * 64 + dd] : 0.0f;
    float ss = v * v;
    ss += __shfl_xor(ss, 1);  ss += __shfl_xor(ss, 2);
    ss += __shfl_xor(ss, 4);  ss += __shfl_xor(ss, 8);
    ss += __shfl_xor(ss, 16); ss += __shfl_xor(ss, 32);
    float inv = 1.0f / (sqrtf(ss) + EPS);
    __builtin_nontemporal_store(v * inv,
        &out[(((size_t)(H_DIM * B_DIM + b) * TP1 + t) << 6) + dd]);
  }
}

// block = (h, b-pair, 128 rows), 512 threads = 8 waves: wm = w&1 owns a
// 64-row half (tw = t0 + 64*wm), wb = (w>>1)&1 owns one b, wk = w>>2
// K-splits the BK=128 step (wave chunks c = 128*it + 64*wk + 32*kkl).
// HALVED BARRIER-PAIR COUNT: every round since R1 was neutral; the per-step
// model time = steps*(F+W) with F ~2400cyc fixed (stage chain + barrier
// convergence, TLP-insensitive per R5) fits all 6 rounds. BK=128 cuts
// per-CU barrier-pairs 39 -> 19 (balanced pairs: lvl bijection
// k<8?k:(k<16?23-k:16) pairs (k,15-k), NS sums = 19 on every CU).
// 2 LDS buffers of 46KB (A 14KB sliding window + B 2b x 2st x 8KB) = 92KB
// -> 1 block/CU. Counted vmcnt (waves 0-5 issue 6 loads/stage, 6-7 issue 5),
// drain only at tail. K-split reduction reuses staging LDS (R0-proven).
// h = bid&7 pins one head per XCD (L2 set ~2.5MB/XCD).
__global__ __launch_bounds__(512) void toeplitz_mm(const unsigned short* __restrict__ fragA,
                                                   const unsigned short* __restrict__ xT,
                                                   float* __restrict__ out) {
  __shared__ __align__(16) char smem[2][BUFSZ];

  const int lane = threadIdx.x & 63;
  const int w    = threadIdx.x >> 6;      // 0..7
  const int wm   = w & 1;
  const int wb   = (w >> 1) & 1;
  const int wk   = w >> 2;
  const int lm   = lane & 15;
  const int quad = lane >> 4;

  const int bid = blockIdx.x;
  const int h   = bid & 7;
  const int bg  = (bid >> 3) & 3;
  const int k   = bid >> 5;                 // 0..16
  const int lvl = (k < 8) ? k : ((k < 16) ? 23 - k : 16);  // CU-balanced pairing
  const int t0  = T_DIM - lvl * 128;
  const int tw  = t0 + 64 * wm;
  const int b   = bg * 2 + wb;
  const bool active = (tw <= T_DIM);
  const int cap = min(tw + 32, T_DIM);      // last valid 32-chunk base for this wave

  const int NS = (min(t0 + 96, T_DIM) >> 7) + 1;   // BK=128 steps, >= 1

  const unsigned short* fA = fragA + (size_t)h * NFRAG * 512 + lane * 8;

  // Stage step 'it' (K base S = it*128) into smem[bufi]:
  // units 0..13 = A entries P_base..P_base+13 (1KB each), P_base = ((t0-S+32)>>4)+4;
  // units 14..45 = B pieces: (bsel,stsel,p) -> xT[bg*2+bsel][S/64+stsel] piece p.
  // Unit u = w + 8*i: waves 0..5 issue 6 loads, waves 6,7 issue 5.
#define STAGE(bufi, it) do {                                                   \
    int _S = (it) << 7;                                                        \
    int _Pb = ((t0 - _S + 32) >> 4) + 4;                                       \
    const unsigned short* _A = fA + (size_t)_Pb * 512;                         \
    int _st0 = _S >> 6;                                                        \
    char* _lb = &smem[bufi][0];                                                \
    _Pragma("unroll")                                                          \
    for (int _i = 0; _i < 6; ++_i) {                                           \
      int _u = w + _i * 8;                                                     \
      if (_u < 46) {                                                           \
        const unsigned short* _src;                                            \
        if (_u < 14) {                                                         \
          _src = _A + (size_t)_u * 512;                                        \
        } else {                                                               \
          int _v = _u - 14;                                                    \
          int _bsel = _v >> 4, _stsel = (_v >> 3) & 1, _p = _v & 7;            \
          _src = xT + ((size_t)((bg * 2 + _bsel) * NST + _st0 + _stsel) << 12) \
                 + _p * 512 + lane * 8;                                        \
        }                                                                      \
        load_lds16(_src, _lb + _u * 1024);                                     \
      }                                                                        \
    }                                                                          \
  } while (0)

  v4f acc[4][4] = {};  // rows tw+16*mt+4*quad+r, cols 16*nt+lm; this wave's wk half of K

  STAGE(0, 0);
  if (NS > 1) STAGE(1, 1);
  int buf = 0;
  for (int it = 0; it < NS; ++it) {
    // Wait for stage(it) (the older of the <=2 in flight), never drain early.
    if (it < NS - 1) {
      if (w < 6) asm volatile("s_waitcnt vmcnt(6)" ::: "memory");
      else       asm volatile("s_waitcnt vmcnt(5)" ::: "memory");
    } else {
      asm volatile("s_waitcnt vmcnt(0)" ::: "memory");
    }
    __builtin_amdgcn_s_barrier();            // everyone's stage(it) landed
    __builtin_amdgcn_sched_barrier(0);       // no ds_read hoists above this point

    const char* Ab = &smem[buf][0];
    const char* Bb = Ab + AREG + (wb * 2 + wk) * 8192;
    int S = it << 7;
    __builtin_amdgcn_s_setprio(1);
    // A units for this wave: base (4 + 4*wm - 4*wk), entries e=0..5;
    // kkl=0 uses af6[2..5], kkl=1 uses af6[0..3] (chunk c = S + 64*wk + 32*kkl).
    v8s af6[6];
    #pragma unroll
    for (int e = 0; e < 6; ++e)
      af6[e] = *(const v8s*)(Ab + (4 + 4 * wm - 4 * wk + e) * 1024 + lane * 16);
    #pragma unroll
    for (int kkl = 0; kkl < 2; ++kkl) {
      int c = S + 64 * wk + 32 * kkl;
      if (active && c <= cap) {
        v8s bf[4];
        #pragma unroll
        for (int nt = 0; nt < 4; ++nt)
          bf[nt] = *(const v8s*)(Bb + nt * 2048 + lm * 128 +
                                 ((((kkl << 2) | quad) ^ (lm & 7)) << 4));
        #pragma unroll
        for (int mt = 0; mt < 4; ++mt)
          #pragma unroll
          for (int nt = 0; nt < 4; ++nt)
            acc[mt][nt] = __builtin_amdgcn_mfma_f32_16x16x32_bf16(
                af6[(kkl ? 0 : 2) + mt], bf[nt], acc[mt][nt], 0, 0, 0);
      }
    }
    __builtin_amdgcn_s_setprio(0);
    __builtin_amdgcn_sched_barrier(0);
    __builtin_amdgcn_s_barrier();            // all waves done reading smem[buf]
    if (it + 2 < NS) STAGE(buf, it + 2);     // loads fly for a whole step
    buf ^= 1;
  }

  // K-split reduction in LDS (R0-proven pattern), reusing the staging buffers:
  // wk=1 dumps partials; wk=0 reduces + epilogue. 4*64*66*4 = 67.6KB <= 92KB.
  float* red = (float*)&smem[0][0] + (wm * 2 + wb) * (64 * RSTRIDE);
  if (wk == 1) {
    #pragma unroll
    for (int mt = 0; mt < 4; ++mt)
      #pragma unroll
      for (int r = 0; r < 4; ++r) {
        int row = 16 * mt + 4 * quad + r;
        #pragma unroll
        for (int nt = 0; nt < 4; ++nt)
          red[row * RSTRIDE + 16 * nt + lm] = acc[mt][nt][r];
      }
  }
  __syncthreads();
  if (wk != 0) return;

  #pragma unroll
  for (int mt = 0; mt < 4; ++mt) {
    #pragma unroll
    for (int r = 0; r < 4; ++r) {
      int row = 16 * mt + 4 * quad + r;
      #pragma unroll
      for (int nt = 0; nt < 4; ++nt)
        acc[mt][nt][r] += red[row * RSTRIDE + 16 * nt + lm];
    }
  }

  if (!active) return;

  // Epilogue: double l2-norm over dd (softmax Z cancels up to eps ~3e-7).
  // C/D layout: col = lane&15 (dd offset), row = quad*4 + reg.
  #pragma unroll
  for (int mt = 0; mt < 4; ++mt) {
    #pragma unroll
    for (int r = 0; r < 4; ++r) {
      float ss = 0.0f;
      #pragma unroll
      for (int nt = 0; nt < 4; ++nt) { float a = acc[mt][nt][r]; ss += a * a; }
      ss += __shfl_xor(ss, 1);
      ss += __shfl_xor(ss, 2);
      ss += __shfl_xor(ss, 4);
      ss += __shfl_xor(ss, 8);
      int t = tw + 16 * mt + 4 * quad + r;
      if (t <= T_DIM) {
        float n1 = sqrtf(ss);
        float u  = n1 / (n1 + EPS);
        float inv = 1.0f / ((n1 + EPS) * (u + EPS));
        float* op = out + (((size_t)(h * B_DIM + b) * TP1 + t) << 6) + lm;
        #pragma unroll
        for (int nt = 0; nt < 4; ++nt)
          __builtin_nontemporal_store(acc[mt][nt][r] * inv, op + 16 * nt);
      }
    }
  }
#undef STAGE
}

extern "C" void kernel_launch(void* const* d_in, const int* in_sizes, int n_in,
                              void* d_out, int out_size, void* d_ws, size_t ws_size,
                              hipStream_t stream) {
  const float* x = (const float*)d_in[0];   // [8, 2048, 64] fp32
  const float* W = (const float*)d_in[1];   // [2048, 8] fp32
  float* out = (float*)d_out;               // [9, 8, 2049, 64] fp32

  unsigned short* xT    = (unsigned short*)d_ws;                    // 8*34*8192 = 2,228,224 B
  unsigned short* fragA = (unsigned short*)((char*)d_ws + 2228224); // 8*148*1024 = 1,212,416 B

  hipLaunchKernelGGL(prep, dim3(J1_BLOCKS + J2_BLOCKS + J3_BLOCKS), dim3(256), 0, stream,
                     x, W, fragA, xT, out);
  hipLaunchKernelGGL(toeplitz_mm, dim3(MM_BLOCKS), dim3(512), 0, stream,
                     fragA, xT, out);
}